// Round 18
// baseline (158.534 us; speedup 1.0000x reference)
//
#include <hip/hip_runtime.h>
#include <math.h>

#define CLASSES 8
#define SIZE 512
#define ISZ 512
#define CSZ 512
#define BATCH 64
#define CMS 4
#define NBUCKET 16
#define LR 0.01f
#define WCLIP 5.0f
#define WSTRIDE 516    // W gather: banks 4*(idx+off)%32 -> worst 2-way (free)

// ---------------- kernel 1: pack (R4/R11 verbatim) ----------------
// Lt    (B, C*I)      : Lt[b*4096 + ci]                  = logits[ci, b]
// Lpk   (C*I/4, B, 4) : Lpk[(ci>>2)*256 + 4*b + (ci&3)]  = logits[ci, b]
// ctxT4 (D/4, B, 4)   : ctxT4[(d>>2)*256 + 4*b + (d&3)]  = context[b, d]
__global__ __launch_bounds__(256) void pack_pre(
    const float* __restrict__ logits,    // (C*I, B)
    const float* __restrict__ context,   // (B, D)
    float* __restrict__ Lt,
    float* __restrict__ Lpk,
    float* __restrict__ ctxT4)
{
    __shared__ float t[64][65];
    const int bid  = blockIdx.x;
    const int lane = threadIdx.x & 63;
    const int w    = threadIdx.x >> 6;
    if (bid < 64) {
        const int r0 = bid << 6;                     // ci base
        #pragma unroll
        for (int rep = 0; rep < 16; ++rep) {
            int rr = w * 16 + rep;
            t[rr][lane] = logits[(size_t)(r0 + rr) * 64 + lane];
        }
        __syncthreads();
        const int ci = r0 + lane;
        #pragma unroll
        for (int rep = 0; rep < 16; ++rep) {
            int b = w * 16 + rep;
            float v = t[lane][b];
            Lt[(size_t)b * 4096 + ci] = v;
            Lpk[(size_t)(ci >> 2) * 256 + 4 * b + (ci & 3)] = v;
        }
    } else {
        const int c0 = (bid - 64) << 6;              // d base
        #pragma unroll
        for (int rep = 0; rep < 16; ++rep) {
            int rr = w * 16 + rep;                   // b
            t[rr][lane] = context[(size_t)rr * 512 + c0 + lane];
        }
        __syncthreads();
        #pragma unroll
        for (int rep = 0; rep < 16; ++rep) {
            int dd = c0 + w * 16 + rep;              // d
            ctxT4[(size_t)(dd >> 2) * 256 + 4 * lane + (dd & 3)] = t[lane][w * 16 + rep];
        }
    }
}

// ---------------- kernel 2: distances -> bucket idx (R8/R11 verbatim, FROZEN) ----------------
// Proven passing + ~35 us. Rules (R1/R3/R10 blowups): cm operand WAVE-UNIFORM
// (readfirstlane -> s_load); ctx operand LANE-CONSECUTIVE (lane=b, coalesced).
// Single-acc 4-term chain, unroll 4. Knife-edge ledger: single-acc chains pass
// (R8, R14); multi-acc chains flip one bucket (R5/R6/R16 -> absmax 6.7e-3).
// DO NOT restructure this kernel further.
__global__ __launch_bounds__(256, 8) void dist_kernel(
    const float* __restrict__ cmaps,     // (C, S, 4, 512)
    const float* __restrict__ cbias,     // (C, S, 4, 1)
    const float* __restrict__ ctxT4,     // packed context
    unsigned char* __restrict__ idxOut)  // (4096, 64)
{
    __shared__ int bits[CMS * BATCH];

    const int tid  = threadIdx.x;
    const int cs   = blockIdx.x;       // c*SIZE + s
    const int lane = tid & 63;
    const int wv   = tid >> 6;
    const int k    = __builtin_amdgcn_readfirstlane(wv);   // wave-uniform

    const float4* cmg = (const float4*)(cmaps + ((size_t)cs * CMS + k) * CSZ);
    {
        const float4* ct4 = (const float4*)ctxT4 + lane;
        float acc = 0.f;
        #pragma unroll 4
        for (int d4 = 0; d4 < 128; ++d4) {
            float4 cm4 = cmg[d4];                    // uniform -> s_load_dwordx4
            float4 cv  = ct4[(size_t)d4 * 64];
            acc += cm4.x * cv.x + cm4.y * cv.y + cm4.z * cv.z + cm4.w * cv.w;
        }
        float bias = cbias[(size_t)cs * CMS + k];
        bits[k * BATCH + lane] = (acc > bias) ? 1 : 0;
    }
    __syncthreads();

    if (wv == 0) {
        int idx_b = bits[lane] | (bits[BATCH + lane] << 1) |
                    (bits[2 * BATCH + lane] << 2) | (bits[3 * BATCH + lane] << 3);
        idxOut[(size_t)cs * BATCH + lane] = (unsigned char)idx_b;
    }
}

// ---------------- kernel 3a: gather-dot -> out, diff, blast (R8 minus update) ----------------
__global__ __launch_bounds__(256, 4) void gln_bc1(
    const float* __restrict__ target,   // (C, B)
    const float* __restrict__ weights,  // (C, S, 16, 512)
    const unsigned char* __restrict__ idxIn,
    const float* __restrict__ Lpk,
    float* __restrict__ out,            // (C, S, B)
    float* __restrict__ diffW,          // (4096, 64)
    int*   __restrict__ blastW)         // (4096, 16)
{
    __shared__ float Wl[NBUCKET * WSTRIDE];   // 33 KB padded rows
    __shared__ float partial[4 * BATCH];

    const int tid  = threadIdx.x;
    const int cs   = blockIdx.x;
    const int c    = cs >> 9;
    const int lane = tid & 63;
    const int wv   = tid >> 6;

    // stage W slice (16 x 512 f32): global -> regs -> padded LDS
    float4 wreg[8];
    const float4* gW = (const float4*)(weights + (size_t)cs * (NBUCKET * ISZ));
    #pragma unroll
    for (int it = 0; it < 8; ++it) wreg[it] = gW[tid + it * 256];

    const int idx_b = idxIn[(size_t)cs * BATCH + lane];

    // last-writers (np last-write-wins): lane j keeps bucket j's answer
    int myblast = -1;
    #pragma unroll
    for (int j = 0; j < NBUCKET; ++j) {
        unsigned long long m = __ballot(idx_b == j);
        int bl = m ? (63 - __clzll(m)) : -1;
        if (lane == j) myblast = bl;
    }
    if (wv == 0 && lane < NBUCKET) blastW[cs * NBUCKET + lane] = myblast;

    #pragma unroll
    for (int it = 0; it < 8; ++it) {
        int f = tid + it * 256;
        *(float4*)&Wl[(f >> 7) * WSTRIDE + (f & 127) * 4] = wreg[it];
    }
    __syncthreads();

    // gather-dot: wave wv covers i in [128*wv, 128*wv+128)  (R8-verbatim)
    {
        const float4* Lp4 = (const float4*)Lpk;
        const int base4 = (c * 128 + wv * 32) * 64 + lane;
        const int wb    = idx_b * WSTRIDE + wv * 128;
        float acc = 0.f;
        #pragma unroll 4
        for (int d4 = 0; d4 < 32; ++d4) {
            float4 w4 = *(const float4*)&Wl[wb + d4 * 4];
            float4 l4 = Lp4[(size_t)base4 + d4 * 64];
            acc += w4.x * l4.x + w4.y * l4.y + w4.z * l4.z + w4.w * l4.w;
        }
        partial[wv * BATCH + lane] = acc;
    }
    __syncthreads();

    // wave 0: out + diff (R8-verbatim summation tree)
    if (wv == 0) {
        float s = partial[lane] + partial[BATCH + lane] +
                  partial[2 * BATCH + lane] + partial[3 * BATCH + lane];
        const float hi = 4.595119850134589f;    // logit(0.99)
        float oc = fminf(fmaxf(s, -hi), hi);
        out[(size_t)cs * BATCH + lane] = oc;
        float sig = 1.f / (1.f + expf(-oc));
        diffW[(size_t)cs * BATCH + lane] = LR * (sig - target[c * BATCH + lane]);
    }
}

// ---------------- kernel 3b: pure streaming update ----------------
// Barrier-free, LDS-free grid-stride over all 8.4M float4 of W. W[f] is
// L3-warm from bc1. blast/diff wave-uniform loads; Lt row coalesced.
// Per-element expression identical to R8's update -> bit-identical outW.
__global__ __launch_bounds__(256) void gln_bc2(
    const float* __restrict__ weights,  // (C, S, 16, 512)
    const float* __restrict__ Lt,       // (B, C*I)
    const float* __restrict__ diffW,    // (4096, 64)
    const int*   __restrict__ blastW,   // (4096, 16)
    float* __restrict__ outW)           // (C, S, 16, 512)
{
    const int tid = threadIdx.x;
    const float4* gW = (const float4*)weights;
    float4* gO = (float4*)outW;
    #pragma unroll
    for (int it = 0; it < 4; ++it) {
        size_t f = ((size_t)blockIdx.x * 4 + it) * 256 + tid;   // f4 index
        int cs   = (int)(f >> 11);
        int rw   = (int)(f >> 7) & 15;
        int col4 = (int)f & 127;
        int c    = cs >> 9;
        float4 w4 = gW[f];
        int bl = blastW[cs * NBUCKET + rw];
        float4 r = w4;
        if (bl >= 0) {
            float coef = diffW[(size_t)cs * BATCH + bl];
            float4 l4  = ((const float4*)Lt)[(size_t)bl * 1024 + c * 128 + col4];
            r.x = fminf(fmaxf(w4.x - coef * l4.x, -WCLIP), WCLIP);
            r.y = fminf(fmaxf(w4.y - coef * l4.y, -WCLIP), WCLIP);
            r.z = fminf(fmaxf(w4.z - coef * l4.z, -WCLIP), WCLIP);
            r.w = fminf(fmaxf(w4.w - coef * l4.w, -WCLIP), WCLIP);
        }
        gO[f] = r;
    }
}

extern "C" void kernel_launch(void* const* d_in, const int* in_sizes, int n_in,
                              void* d_out, int out_size, void* d_ws, size_t ws_size,
                              hipStream_t stream) {
    const float* logits  = (const float*)d_in[0];  // (8,512,64)
    const float* context = (const float*)d_in[1];  // (64,512)
    const float* target  = (const float*)d_in[2];  // (8,64)
    const float* cmaps   = (const float*)d_in[3];  // (8,512,4,512)
    const float* cbias   = (const float*)d_in[4];  // (8,512,4,1)
    const float* weights = (const float*)d_in[5];  // (8,512,16,512)

    float* out  = (float*)d_out;                        // (8,512,64)
    float* outW = out + (size_t)CLASSES * SIZE * BATCH; // (8,512,16,512)

    float* Lt    = (float*)d_ws;                             // 1 MB
    float* Lpk   = Lt + 262144;                              // 1 MB
    float* ctxT4 = Lpk + 262144;                             // 128 KB
    unsigned char* idxb = (unsigned char*)(ctxT4 + 32768);   // 256 KB
    float* diffW = (float*)(idxb + 262144);                  // 1 MB
    int*   blastW = (int*)(diffW + 262144);                  // 256 KB

    pack_pre<<<72, 256, 0, stream>>>(logits, context, Lt, Lpk, ctxT4);
    dist_kernel<<<CLASSES * SIZE, 256, 0, stream>>>(cmaps, cbias, ctxT4, idxb);
    gln_bc1<<<CLASSES * SIZE, 256, 0, stream>>>(target, weights, idxb, Lpk, out, diffW, blastW);
    gln_bc2<<<8192, 256, 0, stream>>>(weights, Lt, diffW, blastW, outW);
}

// Round 19
// 131.234 us; speedup vs baseline: 1.2080x; 1.2080x over previous
//
#include <hip/hip_runtime.h>
#include <math.h>

#define CLASSES 8
#define SIZE 512
#define ISZ 512
#define CSZ 512
#define BATCH 64
#define CMS 4
#define NBUCKET 16
#define LR 0.01f
#define WCLIP 5.0f
#define WSTRIDE 516    // W gather: banks 4*(idx+off)%32 -> worst 2-way (free)

typedef float nt_f4 __attribute__((ext_vector_type(4)));   // for nontemporal builtin

// ---------------- kernel 1: pack (R4 verbatim) ----------------
// Lt    (B, C*I)      : Lt[b*4096 + ci]                  = logits[ci, b]
// Lpk   (C*I/4, B, 4) : Lpk[(ci>>2)*256 + 4*b + (ci&3)]  = logits[ci, b]
// ctxT4 (D/4, B, 4)   : ctxT4[(d>>2)*256 + 4*b + (d&3)]  = context[b, d]
__global__ __launch_bounds__(256) void pack_pre(
    const float* __restrict__ logits,    // (C*I, B)
    const float* __restrict__ context,   // (B, D)
    float* __restrict__ Lt,
    float* __restrict__ Lpk,
    float* __restrict__ ctxT4)
{
    __shared__ float t[64][65];
    const int bid  = blockIdx.x;
    const int lane = threadIdx.x & 63;
    const int w    = threadIdx.x >> 6;
    if (bid < 64) {
        const int r0 = bid << 6;                     // ci base
        #pragma unroll
        for (int rep = 0; rep < 16; ++rep) {
            int rr = w * 16 + rep;
            t[rr][lane] = logits[(size_t)(r0 + rr) * 64 + lane];
        }
        __syncthreads();
        const int ci = r0 + lane;
        #pragma unroll
        for (int rep = 0; rep < 16; ++rep) {
            int b = w * 16 + rep;
            float v = t[lane][b];
            Lt[(size_t)b * 4096 + ci] = v;
            Lpk[(size_t)(ci >> 2) * 256 + 4 * b + (ci & 3)] = v;
        }
    } else {
        const int c0 = (bid - 64) << 6;              // d base
        #pragma unroll
        for (int rep = 0; rep < 16; ++rep) {
            int rr = w * 16 + rep;                   // b
            t[rr][lane] = context[(size_t)rr * 512 + c0 + lane];
        }
        __syncthreads();
        #pragma unroll
        for (int rep = 0; rep < 16; ++rep) {
            int dd = c0 + w * 16 + rep;              // d
            ctxT4[(size_t)(dd >> 2) * 256 + 4 * lane + (dd & 3)] = t[lane][w * 16 + rep];
        }
    }
}

// ---------------- kernel 2: distances -> bucket idx (R8 verbatim, FROZEN) ----------------
// Proven passing. Rules (R1/R3/R10 blowups): cm operand WAVE-UNIFORM
// (readfirstlane -> s_load path); ctx operand LANE-CONSECUTIVE (lane=b, 16B
// stride -> coalesced). Single-acc 4-term chain, unroll 4. Knife-edge ledger:
// single-acc chains pass (R8, R14); multi-acc chains flip one bucket
// (R5/R6/R16 -> absmax 6.7e-3). DO NOT restructure this kernel.
__global__ __launch_bounds__(256, 8) void dist_kernel(
    const float* __restrict__ cmaps,     // (C, S, 4, 512)
    const float* __restrict__ cbias,     // (C, S, 4, 1)
    const float* __restrict__ ctxT4,     // packed context
    unsigned char* __restrict__ idxOut)  // (4096, 64)
{
    __shared__ int bits[CMS * BATCH];

    const int tid  = threadIdx.x;
    const int cs   = blockIdx.x;       // c*SIZE + s
    const int lane = tid & 63;
    const int wv   = tid >> 6;
    const int k    = __builtin_amdgcn_readfirstlane(wv);   // wave-uniform

    const float4* cmg = (const float4*)(cmaps + ((size_t)cs * CMS + k) * CSZ);
    {
        const float4* ct4 = (const float4*)ctxT4 + lane;
        float acc = 0.f;
        #pragma unroll 4
        for (int d4 = 0; d4 < 128; ++d4) {
            float4 cm4 = cmg[d4];                    // uniform -> s_load_dwordx4
            float4 cv  = ct4[(size_t)d4 * 64];
            acc += cm4.x * cv.x + cm4.y * cv.y + cm4.z * cv.z + cm4.w * cv.w;
        }
        float bias = cbias[(size_t)cs * CMS + k];
        bits[k * BATCH + lane] = (acc > bias) ? 1 : 0;
    }
    __syncthreads();

    if (wv == 0) {
        int idx_b = bits[lane] | (bits[BATCH + lane] << 1) |
                    (bits[2 * BATCH + lane] << 2) | (bits[3 * BATCH + lane] << 3);
        idxOut[(size_t)cs * BATCH + lane] = (unsigned char)idx_b;
    }
}

// ---------------- kernel 3: gather-dot + update (R10 verbatim - proven best) ----------------
__global__ __launch_bounds__(256, 4) void gln_bc(
    const float* __restrict__ target,   // (C, B)
    const float* __restrict__ weights,  // (C, S, 16, 512)
    const unsigned char* __restrict__ idxIn,
    const float* __restrict__ Lt,
    const float* __restrict__ Lpk,
    float* __restrict__ out,            // (C, S, B)
    float* __restrict__ outW)           // (C, S, 16, 512)
{
    __shared__ float Wl[NBUCKET * WSTRIDE];   // 33 KB padded rows
    __shared__ float partial[4 * BATCH];
    __shared__ float diff_l[BATCH];

    const int tid  = threadIdx.x;
    const int cs   = blockIdx.x;
    const int c    = cs >> 9;
    const int lane = tid & 63;
    const int wv   = tid >> 6;

    // stage W slice (16 x 512 f32): global -> regs
    float4 wreg[8];
    const float4* gW = (const float4*)(weights + (size_t)cs * (NBUCKET * ISZ));
    #pragma unroll
    for (int it = 0; it < 8; ++it) wreg[it] = gW[tid + it * 256];

    const int idx_b = idxIn[(size_t)cs * BATCH + lane];

    // all 16 last-writers in registers (wave-redundant ballots, no LDS/barrier)
    int blast_r[16];
    #pragma unroll
    for (int j = 0; j < NBUCKET; ++j) {
        unsigned long long m = __ballot(idx_b == j);
        blast_r[j] = m ? (63 - __clzll(m)) : -1;    // np last-write-wins
    }

    // prefetch phase-3 Lt operands (row = (tid>>7) + 2*it, col4 = tid&127);
    // static reg indexing only (runtime-indexed arrays spill to scratch)
    const float* LtC = Lt + (size_t)c * ISZ;
    const int col4 = tid & 127;
    const int hi_half = (tid >> 7) & 1;
    float4 lreg[8];
    int    blv[8];
    #pragma unroll
    for (int it = 0; it < 8; ++it) {
        int bl = hi_half ? blast_r[2 * it + 1] : blast_r[2 * it];
        blv[it] = bl;
        int blc = (bl >= 0) ? bl : 0;
        lreg[it] = ((const float4*)(LtC + (size_t)blc * 4096))[col4];
    }

    // stage W to padded LDS for the gather
    #pragma unroll
    for (int it = 0; it < 8; ++it) {
        int f = tid + it * 256;
        *(float4*)&Wl[(f >> 7) * WSTRIDE + (f & 127) * 4] = wreg[it];
    }
    __syncthreads();

    // gather-dot: wave wv covers i in [128*wv, 128*wv+128)
    {
        const float4* Lp4 = (const float4*)Lpk;
        const int base4 = (c * 128 + wv * 32) * 64 + lane;
        const int wb    = idx_b * WSTRIDE + wv * 128;
        float acc = 0.f;
        #pragma unroll 4
        for (int d4 = 0; d4 < 32; ++d4) {
            float4 w4 = *(const float4*)&Wl[wb + d4 * 4];
            float4 l4 = Lp4[(size_t)base4 + d4 * 64];
            acc += w4.x * l4.x + w4.y * l4.y + w4.z * l4.z + w4.w * l4.w;
        }
        partial[wv * BATCH + lane] = acc;
    }
    __syncthreads();

    // wave 0: out + diff
    if (wv == 0) {
        float s = partial[lane] + partial[BATCH + lane] +
                  partial[2 * BATCH + lane] + partial[3 * BATCH + lane];
        const float hi = 4.595119850134589f;    // logit(0.99)
        float oc = fminf(fmaxf(s, -hi), hi);
        out[(size_t)cs * BATCH + lane] = oc;
        float sig = 1.f / (1.f + expf(-oc));
        diff_l[lane] = LR * (sig - target[c * BATCH + lane]);
    }
    __syncthreads();

    // phase 3: update from regs; nontemporal stores keep W resident in L3
    float* gO = outW + (size_t)cs * (NBUCKET * ISZ);
    #pragma unroll
    for (int it = 0; it < 8; ++it) {
        int f = tid + it * 256;
        float4 w4 = wreg[it];
        int bl = blv[it];
        float4 r = w4;
        if (bl >= 0) {
            float coef = diff_l[bl];
            float4 l4  = lreg[it];
            r.x = fminf(fmaxf(w4.x - coef * l4.x, -WCLIP), WCLIP);
            r.y = fminf(fmaxf(w4.y - coef * l4.y, -WCLIP), WCLIP);
            r.z = fminf(fmaxf(w4.z - coef * l4.z, -WCLIP), WCLIP);
            r.w = fminf(fmaxf(w4.w - coef * l4.w, -WCLIP), WCLIP);
        }
        nt_f4 rv; rv.x = r.x; rv.y = r.y; rv.z = r.z; rv.w = r.w;
        __builtin_nontemporal_store(rv, (nt_f4*)gO + f);
    }
}

extern "C" void kernel_launch(void* const* d_in, const int* in_sizes, int n_in,
                              void* d_out, int out_size, void* d_ws, size_t ws_size,
                              hipStream_t stream) {
    const float* logits  = (const float*)d_in[0];  // (8,512,64)
    const float* context = (const float*)d_in[1];  // (64,512)
    const float* target  = (const float*)d_in[2];  // (8,64)
    const float* cmaps   = (const float*)d_in[3];  // (8,512,4,512)
    const float* cbias   = (const float*)d_in[4];  // (8,512,4,1)
    const float* weights = (const float*)d_in[5];  // (8,512,16,512)

    float* out  = (float*)d_out;                        // (8,512,64)
    float* outW = out + (size_t)CLASSES * SIZE * BATCH; // (8,512,16,512)

    float* Lt    = (float*)d_ws;            // 1 MB
    float* Lpk   = Lt + 262144;             // 1 MB
    float* ctxT4 = Lpk + 262144;            // 128 KB
    unsigned char* idxb = (unsigned char*)(ctxT4 + 32768);   // 256 KB

    pack_pre<<<72, 256, 0, stream>>>(logits, context, Lt, Lpk, ctxT4);
    dist_kernel<<<CLASSES * SIZE, 256, 0, stream>>>(cmaps, cbias, ctxT4, idxb);
    gln_bc<<<CLASSES * SIZE, 256, 0, stream>>>(target, weights, idxb, Lt, Lpk, out, outW);
}